// Round 6
// baseline (72.019 us; speedup 1.0000x reference)
//
#include <hip/hip_runtime.h>
#include <hip/hip_bf16.h>

typedef __attribute__((ext_vector_type(8))) short bf16x8;
typedef __attribute__((ext_vector_type(4))) float f32x4;

#define MFMA16(A,B,C) __builtin_amdgcn_mfma_f32_16x16x32_bf16((A),(B),(C),0,0,0)

static __device__ __forceinline__ f32x4 ld4(const float* p){
  return *(const f32x4*)p;
}
// Single-instruction packed f32->bf16 (RTNE).
static __device__ __forceinline__ unsigned pk2(float a, float b){
  unsigned r;
  asm("v_cvt_pk_bf16_f32 %0, %1, %2" : "=v"(r) : "v"(a), "v"(b));
  return r;
}
static __device__ __forceinline__ bf16x8 mk8(float a,float b,float c,float d,
                                             float e,float f,float g,float h){
  union { bf16x8 v; unsigned u[4]; } r;
  r.u[0]=pk2(a,b); r.u[1]=pk2(c,d); r.u[2]=pk2(e,f); r.u[3]=pk2(g,h);
  return r.v;
}
static __device__ __forceinline__ bf16x8 mk8v(f32x4 a, f32x4 b){
  return mk8(a[0],a[1],a[2],a[3],b[0],b[1],b[2],b[3]);
}
static __device__ __forceinline__ bf16x8 mk8r(f32x4 a, f32x4 b){ // relu + pack
  return mk8(fmaxf(a[0],0.f),fmaxf(a[1],0.f),fmaxf(a[2],0.f),fmaxf(a[3],0.f),
             fmaxf(b[0],0.f),fmaxf(b[1],0.f),fmaxf(b[2],0.f),fmaxf(b[3],0.f));
}
static __device__ __forceinline__ bf16x8 zero8(){
  bf16x8 v;
  #pragma unroll
  for(int i=0;i<8;++i) v[i]=0;
  return v;
}
static __device__ __forceinline__ void keepv(bf16x8& v){ asm("" : "+v"(v)); }
static __device__ __forceinline__ void keepf(f32x4& v){ asm("" : "+v"(v)); }

// Layout conventions (verified C/D layout, learn_hip m89):
//   A-frag: row = lane&15, k = (lane>>4)*8 + j          (weights)
//   B-frag: col = lane&15, k = (lane>>4)*8 + j          (batch activations)
//   C/D   : col = lane&15, row = (lane>>4)*4 + reg
// Scramble sigma: feature h = Mt*16 + hi*4 + reg  <->  k-slot Kt*32 + hi*8 + jj
//   (Kt = Mt>>1, jj = (Mt&1)*4 + reg) applied to Wt2/Wh2 K-cols, z-cols of
//   Wt1/Wh1, and z0, so layer-out feeds layer-in with no cross-lane moves.
//
// R5 post-mortem: LDS-weight rewrite corrupted results (unfound bug) ->
// reverted to the verified R4 all-register structure. This round: 2 batch
// tiles (32 cols) per iteration so each A-fragment feeds 2 independent MFMA
// chains -> halves per-column overhead, doubles dep-chain ILP.
__global__ __launch_bounds__(256, 1) void trm_mfma(
    const float* __restrict__ state, const int* __restrict__ pact,
    const float* __restrict__ z0,
    const float* __restrict__ Wt1, const float* __restrict__ bt1,
    const float* __restrict__ Wt2, const float* __restrict__ bt2,
    const float* __restrict__ Wh1, const float* __restrict__ bh1,
    const float* __restrict__ Wh2, const float* __restrict__ bh2,
    const float* __restrict__ emb, float* __restrict__ out,
    int niters, int wstride)
{
  const int lane = threadIdx.x & 63;
  const int wid  = blockIdx.x * (blockDim.x >> 6) + (threadIdx.x >> 6);
  const int r16  = lane & 15;   // A-row / B-col / C-col
  const int hi   = lane >> 4;   // k-group (inputs) / row-group (C)
  const int he   = hi & 1;      // clamped group for 16-wide (y) loads

  // ---------------- weight / bias / z0 fragments (persistent, pinned) ------
  bf16x8 wt1f[4][4];
  #pragma unroll
  for (int m=0;m<4;++m){
    const float* w = Wt1 + (m*16 + r16)*112;
    wt1f[m][0] = mk8v(ld4(w + hi*4),       ld4(w + 16 + hi*4));   // z (scrambled)
    wt1f[m][1] = mk8v(ld4(w + 32 + hi*8),  ld4(w + 36 + hi*8));   // x[0:32]
    wt1f[m][2] = mk8v(ld4(w + 64 + hi*8),  ld4(w + 68 + hi*8));   // x[32:64]
    bf16x8 yfrag = mk8v(ld4(w + 96 + he*8), ld4(w + 100 + he*8)); // y(16)+pad
    if (hi >= 2) yfrag = zero8();
    wt1f[m][3] = yfrag;
    keepv(wt1f[m][0]); keepv(wt1f[m][1]); keepv(wt1f[m][2]); keepv(wt1f[m][3]);
  }
  bf16x8 wt2f[2][2];
  #pragma unroll
  for (int m=0;m<2;++m){
    const float* w = Wt2 + (m*16 + r16)*64;
    wt2f[m][0] = mk8v(ld4(w + hi*4),      ld4(w + 16 + hi*4));    // h-cols scrambled
    wt2f[m][1] = mk8v(ld4(w + 32 + hi*4), ld4(w + 48 + hi*4));
    keepv(wt2f[m][0]); keepv(wt2f[m][1]);
  }
  bf16x8 wh1f[2][2];
  #pragma unroll
  for (int m=0;m<2;++m){
    const float* w = Wh1 + (m*16 + r16)*48;
    wh1f[m][0] = mk8v(ld4(w + hi*4), ld4(w + 16 + hi*4));         // z (scrambled)
    bf16x8 yfrag = mk8v(ld4(w + 32 + he*8), ld4(w + 36 + he*8));  // y(16)+pad
    if (hi >= 2) yfrag = zero8();
    wh1f[m][1] = yfrag;
    keepv(wh1f[m][0]); keepv(wh1f[m][1]);
  }
  bf16x8 wh2f;
  {
    const float* w = Wh2 + ((r16 < 4) ? r16 : 0)*32;
    bf16x8 t = mk8v(ld4(w + hi*4), ld4(w + 16 + hi*4));           // h-cols scrambled
    if (r16 >= 4) t = zero8();                                    // pad rows 4..15
    wh2f = t;
    keepv(wh2f);
  }
  f32x4 bt1r[4], bt2r[2], bh1r[2], bh2r;
  #pragma unroll
  for (int m=0;m<4;++m){ bt1r[m] = ld4(bt1 + m*16 + hi*4); keepf(bt1r[m]); }
  #pragma unroll
  for (int m=0;m<2;++m){ bt2r[m] = ld4(bt2 + m*16 + hi*4); keepf(bt2r[m]); }
  #pragma unroll
  for (int m=0;m<2;++m){ bh1r[m] = ld4(bh1 + m*16 + hi*4); keepf(bh1r[m]); }
  {
    f32x4 t = ld4(bh2);
    float msk = (hi == 0) ? 1.f : 0.f;
    bh2r = t * msk;
    keepf(bh2r);
  }
  bf16x8 z0f = mk8v(ld4(z0 + hi*4), ld4(z0 + 16 + hi*4));         // scrambled
  keepv(z0f);

  // ---------------- batch loop: 2 tiles (32 cols) per iteration ------------
  int it = wid;
  f32x4 ax0, ax1, ax2, ax3, bx0, bx1, bx2, bx3;
  int aact, bact;
  {
    const int colA = it*32 + r16, colB = colA + 16;
    const float* xa = state + (size_t)colA*64;
    const float* xb = state + (size_t)colB*64;
    ax0 = ld4(xa + hi*8);      ax1 = ld4(xa + hi*8 + 4);
    ax2 = ld4(xa + 32 + hi*8); ax3 = ld4(xa + 36 + hi*8);
    bx0 = ld4(xb + hi*8);      bx1 = ld4(xb + hi*8 + 4);
    bx2 = ld4(xb + 32 + hi*8); bx3 = ld4(xb + 36 + hi*8);
    aact = pact[colA]; bact = pact[colB];
  }

  #pragma unroll 1
  for (; it < niters; it += wstride){
    const int colA = it*32 + r16, colB = colA + 16;

    // pack current x/y; raw regs then die and get reused by the prefetch
    bf16x8 xfA0 = mk8v(ax0, ax1), xfA1 = mk8v(ax2, ax3);
    bf16x8 xfB0 = mk8v(bx0, bx1), xfB1 = mk8v(bx2, bx3);
    bf16x8 yfA, yfB;
    {
      const float* er = emb + aact*16 + he*8;
      yfA = mk8v(ld4(er), ld4(er + 4));
      if (hi >= 2) yfA = zero8();
    }
    {
      const float* er = emb + bact*16 + he*8;
      yfB = mk8v(ld4(er), ld4(er + 4));
      if (hi >= 2) yfB = zero8();
    }

    // prefetch next iteration's state/actions (hides under the MFMA body)
    const int itn = it + wstride;
    if (itn < niters){
      const int cAn = itn*32 + r16, cBn = cAn + 16;
      const float* xa = state + (size_t)cAn*64;
      const float* xb = state + (size_t)cBn*64;
      ax0 = ld4(xa + hi*8);      ax1 = ld4(xa + hi*8 + 4);
      ax2 = ld4(xa + 32 + hi*8); ax3 = ld4(xa + 36 + hi*8);
      bx0 = ld4(xb + hi*8);      bx1 = ld4(xb + hi*8 + 4);
      bx2 = ld4(xb + 32 + hi*8); bx3 = ld4(xb + 36 + hi*8);
      aact = pact[cAn]; bact = pact[cBn];
    }

    bf16x8 zfA = z0f, zfB = z0f;
    f32x4 lgvA, lgvB;

    #pragma unroll
    for (int s = 0; s < 2; ++s){
      #pragma unroll
      for (int itr = 0; itr < 2; ++itr){
        f32x4 cA0=bt1r[0], cA1=bt1r[1], cA2=bt1r[2], cA3=bt1r[3];
        f32x4 cB0=bt1r[0], cB1=bt1r[1], cB2=bt1r[2], cB3=bt1r[3];
        cA0=MFMA16(wt1f[0][0],zfA,cA0);  cB0=MFMA16(wt1f[0][0],zfB,cB0);
        cA1=MFMA16(wt1f[1][0],zfA,cA1);  cB1=MFMA16(wt1f[1][0],zfB,cB1);
        cA2=MFMA16(wt1f[2][0],zfA,cA2);  cB2=MFMA16(wt1f[2][0],zfB,cB2);
        cA3=MFMA16(wt1f[3][0],zfA,cA3);  cB3=MFMA16(wt1f[3][0],zfB,cB3);
        cA0=MFMA16(wt1f[0][1],xfA0,cA0); cB0=MFMA16(wt1f[0][1],xfB0,cB0);
        cA1=MFMA16(wt1f[1][1],xfA0,cA1); cB1=MFMA16(wt1f[1][1],xfB0,cB1);
        cA2=MFMA16(wt1f[2][1],xfA0,cA2); cB2=MFMA16(wt1f[2][1],xfB0,cB2);
        cA3=MFMA16(wt1f[3][1],xfA0,cA3); cB3=MFMA16(wt1f[3][1],xfB0,cB3);
        cA0=MFMA16(wt1f[0][2],xfA1,cA0); cB0=MFMA16(wt1f[0][2],xfB1,cB0);
        cA1=MFMA16(wt1f[1][2],xfA1,cA1); cB1=MFMA16(wt1f[1][2],xfB1,cB1);
        cA2=MFMA16(wt1f[2][2],xfA1,cA2); cB2=MFMA16(wt1f[2][2],xfB1,cB2);
        cA3=MFMA16(wt1f[3][2],xfA1,cA3); cB3=MFMA16(wt1f[3][2],xfB1,cB3);
        cA0=MFMA16(wt1f[0][3],yfA,cA0);  cB0=MFMA16(wt1f[0][3],yfB,cB0);
        cA1=MFMA16(wt1f[1][3],yfA,cA1);  cB1=MFMA16(wt1f[1][3],yfB,cB1);
        cA2=MFMA16(wt1f[2][3],yfA,cA2);  cB2=MFMA16(wt1f[2][3],yfB,cB2);
        cA3=MFMA16(wt1f[3][3],yfA,cA3);  cB3=MFMA16(wt1f[3][3],yfB,cB3);
        bf16x8 hA0 = mk8r(cA0, cA1), hA1 = mk8r(cA2, cA3);
        bf16x8 hB0 = mk8r(cB0, cB1), hB1 = mk8r(cB2, cB3);
        f32x4 dA0=bt2r[0], dA1=bt2r[1], dB0=bt2r[0], dB1=bt2r[1];
        dA0=MFMA16(wt2f[0][0],hA0,dA0); dB0=MFMA16(wt2f[0][0],hB0,dB0);
        dA1=MFMA16(wt2f[1][0],hA0,dA1); dB1=MFMA16(wt2f[1][0],hB0,dB1);
        dA0=MFMA16(wt2f[0][1],hA1,dA0); dB0=MFMA16(wt2f[0][1],hB1,dB0);
        dA1=MFMA16(wt2f[1][1],hA1,dA1); dB1=MFMA16(wt2f[1][1],hB1,dB1);
        zfA = mk8v(dA0, dA1); zfB = mk8v(dB0, dB1);
      }
      f32x4 gA0=bh1r[0], gA1=bh1r[1], gB0=bh1r[0], gB1=bh1r[1];
      gA0=MFMA16(wh1f[0][0],zfA,gA0); gB0=MFMA16(wh1f[0][0],zfB,gB0);
      gA1=MFMA16(wh1f[1][0],zfA,gA1); gB1=MFMA16(wh1f[1][0],zfB,gB1);
      gA0=MFMA16(wh1f[0][1],yfA,gA0); gB0=MFMA16(wh1f[0][1],yfB,gB0);
      gA1=MFMA16(wh1f[1][1],yfA,gA1); gB1=MFMA16(wh1f[1][1],yfB,gB1);
      bf16x8 hhA = mk8r(gA0, gA1), hhB = mk8r(gB0, gB1);
      f32x4 clA = bh2r, clB = bh2r;
      clA = MFMA16(wh2f, hhA, clA);
      clB = MFMA16(wh2f, hhB, clB);
      lgvA = clA; lgvB = clB;
      if (s == 0){
        {
          float l0=__shfl(clA[0],r16), l1=__shfl(clA[1],r16);
          float l2=__shfl(clA[2],r16), l3=__shfl(clA[3],r16);
          float mx = fmaxf(fmaxf(l0,l1), fmaxf(l2,l3));
          float p0=__expf(l0-mx), p1=__expf(l1-mx);
          float p2=__expf(l2-mx), p3=__expf(l3-mx);
          float inv = 1.f/(p0+p1+p2+p3);
          p0*=inv; p1*=inv; p2*=inv; p3*=inv;
          const float* eb = emb + he*8;
          f32x4 ya = ld4(eb)*p0    + ld4(eb+16)*p1 +
                     ld4(eb+32)*p2 + ld4(eb+48)*p3;
          f32x4 yb = ld4(eb+4)*p0  + ld4(eb+20)*p1 +
                     ld4(eb+36)*p2 + ld4(eb+52)*p3;
          yfA = mk8v(ya, yb);
          if (hi >= 2) yfA = zero8();
        }
        {
          float l0=__shfl(clB[0],r16), l1=__shfl(clB[1],r16);
          float l2=__shfl(clB[2],r16), l3=__shfl(clB[3],r16);
          float mx = fmaxf(fmaxf(l0,l1), fmaxf(l2,l3));
          float p0=__expf(l0-mx), p1=__expf(l1-mx);
          float p2=__expf(l2-mx), p3=__expf(l3-mx);
          float inv = 1.f/(p0+p1+p2+p3);
          p0*=inv; p1*=inv; p2*=inv; p3*=inv;
          const float* eb = emb + he*8;
          f32x4 ya = ld4(eb)*p0    + ld4(eb+16)*p1 +
                     ld4(eb+32)*p2 + ld4(eb+48)*p3;
          f32x4 yb = ld4(eb+4)*p0  + ld4(eb+20)*p1 +
                     ld4(eb+36)*p2 + ld4(eb+52)*p3;
          yfB = mk8v(ya, yb);
          if (hi >= 2) yfB = zero8();
        }
      }
    }
    if (hi == 0){
      *(f32x4*)(out + (size_t)colA*4) = lgvA;
      *(f32x4*)(out + (size_t)colB*4) = lgvB;
    }
  }
}

extern "C" void kernel_launch(void* const* d_in, const int* in_sizes, int n_in,
                              void* d_out, int out_size, void* d_ws, size_t ws_size,
                              hipStream_t stream) {
  const float* state = (const float*)d_in[0];
  const int*   pact  = (const int*)  d_in[1];
  const float* z0    = (const float*)d_in[2];
  const float* Wt1   = (const float*)d_in[3];
  const float* bt1   = (const float*)d_in[4];
  const float* Wt2   = (const float*)d_in[5];
  const float* bt2   = (const float*)d_in[6];
  const float* Wh1   = (const float*)d_in[7];
  const float* bh1   = (const float*)d_in[8];
  const float* Wh2   = (const float*)d_in[9];
  const float* bh2   = (const float*)d_in[10];
  const float* emb   = (const float*)d_in[11];
  float* out = (float*)d_out;

  const int B = in_sizes[0] / 64;         // 524288
  const int niters = B / 32;              // 16384 (2 tiles of 16 per iter)
  const int blocks = 1024;                // 4 waves/block -> 4096 waves, 4 iters each
  const int wstride = blocks * 4;
  trm_mfma<<<blocks, 256, 0, stream>>>(state, pact, z0, Wt1, bt1, Wt2, bt2,
                                       Wh1, bh1, Wh2, bh2, emb, out,
                                       niters, wstride);
}

// Round 7
// 63.224 us; speedup vs baseline: 1.1391x; 1.1391x over previous
//
#include <hip/hip_runtime.h>
#include <hip/hip_bf16.h>

typedef __attribute__((ext_vector_type(8))) short bf16x8;
typedef __attribute__((ext_vector_type(4))) float f32x4;

#define MFMA16(A,B,C) __builtin_amdgcn_mfma_f32_16x16x32_bf16((A),(B),(C),0,0,0)

static __device__ __forceinline__ f32x4 ld4(const float* p){
  return *(const f32x4*)p;
}
// Single-instruction packed f32->bf16 (RTNE).
static __device__ __forceinline__ unsigned pk2(float a, float b){
  unsigned r;
  asm("v_cvt_pk_bf16_f32 %0, %1, %2" : "=v"(r) : "v"(a), "v"(b));
  return r;
}
static __device__ __forceinline__ bf16x8 mk8(float a,float b,float c,float d,
                                             float e,float f,float g,float h){
  union { bf16x8 v; unsigned u[4]; } r;
  r.u[0]=pk2(a,b); r.u[1]=pk2(c,d); r.u[2]=pk2(e,f); r.u[3]=pk2(g,h);
  return r.v;
}
static __device__ __forceinline__ bf16x8 mk8v(f32x4 a, f32x4 b){
  return mk8(a[0],a[1],a[2],a[3],b[0],b[1],b[2],b[3]);
}
static __device__ __forceinline__ bf16x8 mk8r(f32x4 a, f32x4 b){ // relu + pack
  return mk8(fmaxf(a[0],0.f),fmaxf(a[1],0.f),fmaxf(a[2],0.f),fmaxf(a[3],0.f),
             fmaxf(b[0],0.f),fmaxf(b[1],0.f),fmaxf(b[2],0.f),fmaxf(b[3],0.f));
}
static __device__ __forceinline__ bf16x8 zero8(){
  bf16x8 v;
  #pragma unroll
  for(int i=0;i<8;++i) v[i]=0;
  return v;
}
// AGPR pin: places persistent fragments in the accumulator file. MFMA reads
// A/B/C operands directly from AGPRs (cdna4_isa §10), so residency costs ZERO
// VALU. R2-R6 post-mortem: "+v" pins / no pins both led to v_accvgpr shuttle
// traffic (~800 extra VALU/tile) because the allocator wants these in AGPRs.
static __device__ __forceinline__ void keepa(bf16x8& v){ asm("" : "+a"(v)); }
static __device__ __forceinline__ void keepaf(f32x4& v){ asm("" : "+a"(v)); }

// Layout conventions (verified C/D layout, learn_hip m89):
//   A-frag: row = lane&15, k = (lane>>4)*8 + j          (weights)
//   B-frag: col = lane&15, k = (lane>>4)*8 + j          (batch activations)
//   C/D   : col = lane&15, row = (lane>>4)*4 + reg
// Scramble sigma: feature h = Mt*16 + hi*4 + reg  <->  k-slot Kt*32 + hi*8 + jj
//   (Kt = Mt>>1, jj = (Mt&1)*4 + reg) applied to Wt2/Wh2 K-cols, z-cols of
//   Wt1/Wh1, and z0, so layer-out feeds layer-in with no cross-lane moves.
__global__ __launch_bounds__(256, 1) void trm_mfma(
    const float* __restrict__ state, const int* __restrict__ pact,
    const float* __restrict__ z0,
    const float* __restrict__ Wt1, const float* __restrict__ bt1,
    const float* __restrict__ Wt2, const float* __restrict__ bt2,
    const float* __restrict__ Wh1, const float* __restrict__ bh1,
    const float* __restrict__ Wh2, const float* __restrict__ bh2,
    const float* __restrict__ emb, float* __restrict__ out,
    int ntiles, int wstride)
{
  const int lane = threadIdx.x & 63;
  const int wid  = blockIdx.x * (blockDim.x >> 6) + (threadIdx.x >> 6);
  const int r16  = lane & 15;   // A-row / B-col / C-col
  const int hi   = lane >> 4;   // k-group (inputs) / row-group (C)
  const int he   = hi & 1;      // clamped group for 16-wide (y) loads

  // ------------- persistent fragments, pinned into the AGPR file -----------
  bf16x8 wt1f[4][4];
  #pragma unroll
  for (int m=0;m<4;++m){
    const float* w = Wt1 + (m*16 + r16)*112;
    wt1f[m][0] = mk8v(ld4(w + hi*4),       ld4(w + 16 + hi*4));   // z (scrambled)
    wt1f[m][1] = mk8v(ld4(w + 32 + hi*8),  ld4(w + 36 + hi*8));   // x[0:32]
    wt1f[m][2] = mk8v(ld4(w + 64 + hi*8),  ld4(w + 68 + hi*8));   // x[32:64]
    bf16x8 yfrag = mk8v(ld4(w + 96 + he*8), ld4(w + 100 + he*8)); // y(16)+pad
    if (hi >= 2) yfrag = zero8();
    wt1f[m][3] = yfrag;
    keepa(wt1f[m][0]); keepa(wt1f[m][1]); keepa(wt1f[m][2]); keepa(wt1f[m][3]);
  }
  bf16x8 wt2f[2][2];
  #pragma unroll
  for (int m=0;m<2;++m){
    const float* w = Wt2 + (m*16 + r16)*64;
    wt2f[m][0] = mk8v(ld4(w + hi*4),      ld4(w + 16 + hi*4));    // h-cols scrambled
    wt2f[m][1] = mk8v(ld4(w + 32 + hi*4), ld4(w + 48 + hi*4));
    keepa(wt2f[m][0]); keepa(wt2f[m][1]);
  }
  bf16x8 wh1f[2][2];
  #pragma unroll
  for (int m=0;m<2;++m){
    const float* w = Wh1 + (m*16 + r16)*48;
    wh1f[m][0] = mk8v(ld4(w + hi*4), ld4(w + 16 + hi*4));         // z (scrambled)
    bf16x8 yfrag = mk8v(ld4(w + 32 + he*8), ld4(w + 36 + he*8));  // y(16)+pad
    if (hi >= 2) yfrag = zero8();
    wh1f[m][1] = yfrag;
    keepa(wh1f[m][0]); keepa(wh1f[m][1]);
  }
  bf16x8 wh2f;
  {
    const float* w = Wh2 + ((r16 < 4) ? r16 : 0)*32;
    bf16x8 t = mk8v(ld4(w + hi*4), ld4(w + 16 + hi*4));           // h-cols scrambled
    if (r16 >= 4) t = zero8();                                    // pad rows 4..15
    wh2f = t;
    keepa(wh2f);
  }
  // Biases are ONLY used as MFMA C-operands (bias-as-C) -> AGPR residency
  // is free for them too.
  f32x4 bt1r[4], bt2r[2], bh1r[2], bh2r;
  #pragma unroll
  for (int m=0;m<4;++m){ bt1r[m] = ld4(bt1 + m*16 + hi*4); keepaf(bt1r[m]); }
  #pragma unroll
  for (int m=0;m<2;++m){ bt2r[m] = ld4(bt2 + m*16 + hi*4); keepaf(bt2r[m]); }
  #pragma unroll
  for (int m=0;m<2;++m){ bh1r[m] = ld4(bh1 + m*16 + hi*4); keepaf(bh1r[m]); }
  {
    f32x4 t = ld4(bh2);
    float msk = (hi == 0) ? 1.f : 0.f;
    bh2r = t * msk;
    keepaf(bh2r);
  }
  bf16x8 z0f = mk8v(ld4(z0 + hi*4), ld4(z0 + 16 + hi*4));         // scrambled
  keepa(z0f);

  // ---------------- batch-tile loop (16 cols per wave-iteration) -----------
  int t = wid;
  f32x4 cx0, cx1, cx2, cx3; int cact;
  {
    const int col = t*16 + r16;
    const float* xr = state + (size_t)col*64;
    cx0 = ld4(xr + hi*8);      cx1 = ld4(xr + hi*8 + 4);
    cx2 = ld4(xr + 32 + hi*8); cx3 = ld4(xr + 36 + hi*8);
    cact = pact[col];
  }

  #pragma unroll 1
  for (; t < ntiles; t += wstride){
    const int col = t*16 + r16;
    bf16x8 xf0 = mk8v(cx0, cx1);
    bf16x8 xf1 = mk8v(cx2, cx3);
    bf16x8 yf;
    {
      const float* er = emb + cact*16 + he*8;
      yf = mk8v(ld4(er), ld4(er + 4));
      if (hi >= 2) yf = zero8();
    }

    // prefetch next tile's state/action (hides under the MFMA body)
    const int tn = t + wstride;
    if (tn < ntiles){
      const int coln = tn*16 + r16;
      const float* xrn = state + (size_t)coln*64;
      cx0 = ld4(xrn + hi*8);      cx1 = ld4(xrn + hi*8 + 4);
      cx2 = ld4(xrn + 32 + hi*8); cx3 = ld4(xrn + 36 + hi*8);
      cact = pact[coln];
    }

    bf16x8 zf = z0f;
    f32x4 lgv;

    #pragma unroll
    for (int s=0;s<2;++s){
      #pragma unroll
      for (int itr=0; itr<2; ++itr){
        // bias-as-C: first MFMA of each chain takes the bias as src2 (no copy)
        f32x4 c0 = MFMA16(wt1f[0][0], zf, bt1r[0]);
        f32x4 c1 = MFMA16(wt1f[1][0], zf, bt1r[1]);
        f32x4 c2 = MFMA16(wt1f[2][0], zf, bt1r[2]);
        f32x4 c3 = MFMA16(wt1f[3][0], zf, bt1r[3]);
        c0=MFMA16(wt1f[0][1], xf0, c0); c1=MFMA16(wt1f[1][1], xf0, c1);
        c2=MFMA16(wt1f[2][1], xf0, c2); c3=MFMA16(wt1f[3][1], xf0, c3);
        c0=MFMA16(wt1f[0][2], xf1, c0); c1=MFMA16(wt1f[1][2], xf1, c1);
        c2=MFMA16(wt1f[2][2], xf1, c2); c3=MFMA16(wt1f[3][2], xf1, c3);
        c0=MFMA16(wt1f[0][3], yf,  c0); c1=MFMA16(wt1f[1][3], yf,  c1);
        c2=MFMA16(wt1f[2][3], yf,  c2); c3=MFMA16(wt1f[3][3], yf,  c3);
        bf16x8 h0 = mk8r(c0, c1);             // K-tile 0 of hidden (scrambled)
        bf16x8 h1 = mk8r(c2, c3);             // K-tile 1
        f32x4 d0 = MFMA16(wt2f[0][0], h0, bt2r[0]);
        f32x4 d1 = MFMA16(wt2f[1][0], h0, bt2r[1]);
        d0=MFMA16(wt2f[0][1], h1, d0);
        d1=MFMA16(wt2f[1][1], h1, d1);
        zf = mk8v(d0, d1);                    // z (scrambled), in-lane
      }
      f32x4 g0 = MFMA16(wh1f[0][0], zf, bh1r[0]);
      f32x4 g1 = MFMA16(wh1f[1][0], zf, bh1r[1]);
      g0=MFMA16(wh1f[0][1], yf, g0);
      g1=MFMA16(wh1f[1][1], yf, g1);
      bf16x8 hh = mk8r(g0, g1);
      f32x4 cl = MFMA16(wh2f, hh, bh2r);      // logits: hi==0 lanes, regs 0..3
      lgv = cl;
      if (s == 0){
        float l0 = __shfl(cl[0], r16), l1 = __shfl(cl[1], r16);
        float l2 = __shfl(cl[2], r16), l3 = __shfl(cl[3], r16);
        float mx = fmaxf(fmaxf(l0,l1), fmaxf(l2,l3));
        float p0=__expf(l0-mx), p1=__expf(l1-mx);
        float p2=__expf(l2-mx), p3=__expf(l3-mx);
        float inv = 1.f/(p0+p1+p2+p3);
        p0*=inv; p1*=inv; p2*=inv; p3*=inv;
        const float* eb = emb + he*8;
        f32x4 ya = ld4(eb)*p0      + ld4(eb+16)*p1 +
                   ld4(eb+32)*p2   + ld4(eb+48)*p3;
        f32x4 yb = ld4(eb+4)*p0    + ld4(eb+20)*p1 +
                   ld4(eb+36)*p2   + ld4(eb+52)*p3;
        yf = mk8v(ya, yb);
        if (hi >= 2) yf = zero8();
      }
    }
    if (hi == 0) *(f32x4*)(out + (size_t)col*4) = lgv;
  }
}

extern "C" void kernel_launch(void* const* d_in, const int* in_sizes, int n_in,
                              void* d_out, int out_size, void* d_ws, size_t ws_size,
                              hipStream_t stream) {
  const float* state = (const float*)d_in[0];
  const int*   pact  = (const int*)  d_in[1];
  const float* z0    = (const float*)d_in[2];
  const float* Wt1   = (const float*)d_in[3];
  const float* bt1   = (const float*)d_in[4];
  const float* Wt2   = (const float*)d_in[5];
  const float* bt2   = (const float*)d_in[6];
  const float* Wh1   = (const float*)d_in[7];
  const float* bh1   = (const float*)d_in[8];
  const float* Wh2   = (const float*)d_in[9];
  const float* bh2   = (const float*)d_in[10];
  const float* emb   = (const float*)d_in[11];
  float* out = (float*)d_out;

  const int B = in_sizes[0] / 64;         // 524288
  const int ntiles = B / 16;              // 32768 16-col tiles
  const int blocks = 1024;                // 4 waves/block -> 4096 waves, 8 tiles each
  const int wstride = blocks * 4;
  trm_mfma<<<blocks, 256, 0, stream>>>(state, pact, z0, Wt1, bt1, Wt2, bt2,
                                       Wh1, bh1, Wh2, bh2, emb, out,
                                       ntiles, wstride);
}